// Round 5
// baseline (964.507 us; speedup 1.0000x reference)
//
#include <hip/hip_runtime.h>
#include <hip/hip_bf16.h>
#include <cstdint>

typedef __attribute__((ext_vector_type(8))) short bf16x8;
typedef __attribute__((ext_vector_type(4))) float f32x4;

#define H_   16
#define HKV_ 2
#define DD   256
#define BB   2
#define SS   2048
#define EE   2048
#define MTOK (BB*SS)     // 4096
#define HD   (H_*DD)     // 4096

static __device__ __forceinline__ unsigned short f2bf(float f) {
  union { float f; unsigned u; } v; v.f = f;
  unsigned r = v.u + 0x7fffu + ((v.u >> 16) & 1u);
  return (unsigned short)(r >> 16);
}
static __device__ __forceinline__ float bf2f(unsigned short h) {
  union { unsigned u; float f; } v; v.u = ((unsigned)h) << 16;
  return v.f;
}

static __device__ __forceinline__ void gll16(const unsigned short* g, unsigned short* l) {
  __builtin_amdgcn_global_load_lds(
      (const __attribute__((address_space(1))) unsigned int*)g,
      (__attribute__((address_space(3))) unsigned int*)l, 16, 0, 0);
}

// ---------------- fp32 -> bf16 convert (vectorized) ----------------
__global__ __launch_bounds__(256) void ga_cvt(const float* __restrict__ in,
                                              unsigned short* __restrict__ out, int n) {
  int i = (blockIdx.x * 256 + threadIdx.x) * 4;
  if (i >= n) return;
  float4 v = *(const float4*)(in + i);
  ushort4 o;
  o.x = f2bf(v.x); o.y = f2bf(v.y); o.z = f2bf(v.z); o.w = f2bf(v.w);
  *(ushort4*)(out + i) = o;
}

// -------- transpose+convert: out[c][r] = bf16(in[r][c]), in is R x C --------
__global__ __launch_bounds__(256) void ga_transpose_wo(const float* __restrict__ in,
                                                       unsigned short* __restrict__ out,
                                                       int R, int C) {
  __shared__ float tile[64][65];
  int c0 = blockIdx.x * 64, r0 = blockIdx.y * 64;
  int tid = threadIdx.x;
#pragma unroll
  for (int it = 0; it < 16; ++it) {
    int idx = it * 256 + tid; int rr = idx >> 6, cc = idx & 63;
    tile[rr][cc] = in[(size_t)(r0 + rr) * C + c0 + cc];
  }
  __syncthreads();
#pragma unroll
  for (int it = 0; it < 16; ++it) {
    int idx = it * 256 + tid; int rr = idx >> 6, cc = idx & 63;
    out[(size_t)(c0 + rr) * R + r0 + cc] = f2bf(tile[cc][rr]);
  }
}

// -------- pack [Wq|Wk|Wv|Wg] transposed: out[n][k], n in [0,9216) --------
__global__ __launch_bounds__(256) void ga_pack_qkvg(const float* __restrict__ Wq,
                                                    const float* __restrict__ Wk,
                                                    const float* __restrict__ Wv,
                                                    const float* __restrict__ Wg,
                                                    unsigned short* __restrict__ out) {
  __shared__ float tile[64][65];
  int n0 = blockIdx.x * 64, k0 = blockIdx.y * 64;
  const float* src; int C, cbase;
  if (n0 < 4096)      { src = Wq; C = 4096; cbase = n0; }
  else if (n0 < 4608) { src = Wk; C = 512;  cbase = n0 - 4096; }
  else if (n0 < 5120) { src = Wv; C = 512;  cbase = n0 - 4608; }
  else                { src = Wg; C = 4096; cbase = n0 - 5120; }
  int tid = threadIdx.x;
#pragma unroll
  for (int it = 0; it < 16; ++it) {
    int idx = it * 256 + tid; int rr = idx >> 6, cc = idx & 63;
    tile[rr][cc] = src[(size_t)(k0 + rr) * C + cbase + cc];
  }
  __syncthreads();
#pragma unroll
  for (int it = 0; it < 16; ++it) {
    int idx = it * 256 + tid; int rr = idx >> 6, cc = idx & 63;
    out[(size_t)(n0 + rr) * EE + k0 + cc] = f2bf(tile[cc][rr]);
  }
}

// -------- shared 128x128 GEMM main loop (A[M][K] @ Bt[N][K]^T) --------
template<int KDIM>
static __device__ __forceinline__ void gemm_loop(const unsigned short* __restrict__ A,
                                                 const unsigned short* __restrict__ Bt,
                                                 unsigned short* As, unsigned short* Bs,
                                                 int m0, int n0, f32x4 acc[4][4]) {
  int tid = threadIdx.x, lane = tid & 63, wid = tid >> 6;
  int wr = wid >> 1, wc = wid & 1;
  for (int k0 = 0; k0 < KDIM; k0 += 32) {
    __syncthreads();
#pragma unroll
    for (int r2 = 0; r2 < 2; ++r2) {
      int c = r2 * 256 + wid * 64 + lane;
      int row = c >> 2, cb = c & 3;
      gll16(A  + (size_t)(m0 + row) * KDIM + k0 + cb * 8, As + (r2 * 256 + wid * 64) * 8);
      gll16(Bt + (size_t)(n0 + row) * KDIM + k0 + cb * 8, Bs + (r2 * 256 + wid * 64) * 8);
    }
    __syncthreads();
    bf16x8 af[4], bfv[4];
#pragma unroll
    for (int mf = 0; mf < 4; ++mf)
      af[mf] = *(const bf16x8*)&As[(wr * 64 + mf * 16 + (lane & 15)) * 32 + (lane >> 4) * 8];
#pragma unroll
    for (int nf = 0; nf < 4; ++nf)
      bfv[nf] = *(const bf16x8*)&Bs[(wc * 64 + nf * 16 + (lane & 15)) * 32 + (lane >> 4) * 8];
#pragma unroll
    for (int mf = 0; mf < 4; ++mf)
#pragma unroll
      for (int nf = 0; nf < 4; ++nf)
        acc[mf][nf] = __builtin_amdgcn_mfma_f32_16x16x32_bf16(af[mf], bfv[nf], acc[mf][nf], 0, 0, 0);
  }
}

// bijective XCD swizzle over the linear grid (nwg divisible by 8)
static __device__ __forceinline__ void xcd_swizzle_128(int& n0, int& m0) {
  int gx = gridDim.x;
  int nwg = gx * gridDim.y;
  int lin = blockIdx.y * gx + blockIdx.x;
  int cpx = nwg >> 3;
  int swz = (lin & 7) * cpx + (lin >> 3);
  n0 = (swz % gx) * 128;
  m0 = (swz / gx) * 128;
}

// -------- GEMM1: X @ Wcat^T with fused RoPE/sigmoid scatter epilogue --------
// V is written TRANSPOSED to global: vt[b][hk][d][s]  (enables plain-load PV)
__global__ __launch_bounds__(256) void ga_gemm_qkvg(const unsigned short* __restrict__ A,
                                                    const unsigned short* __restrict__ Bt,
                                                    unsigned short* __restrict__ qo,
                                                    unsigned short* __restrict__ ko,
                                                    unsigned short* __restrict__ vo,
                                                    unsigned short* __restrict__ go) {
  __shared__ unsigned short As[128 * 32];
  __shared__ unsigned short Bs[128 * 32];
  int tid = threadIdx.x, lane = tid & 63, wid = tid >> 6;
  int wr = wid >> 1, wc = wid & 1;
  int n0, m0;
  xcd_swizzle_128(n0, m0);
  f32x4 acc[4][4];
  f32x4 z = {0.f, 0.f, 0.f, 0.f};
#pragma unroll
  for (int i = 0; i < 4; ++i)
#pragma unroll
    for (int j = 0; j < 4; ++j) acc[i][j] = z;

  gemm_loop<EE>(A, Bt, As, Bs, m0, n0, acc);

  int li = lane & 15, lg = lane >> 4;
  int nb = n0 + wc * 64;      // 64-aligned col block (single region, single head)
  int mb = m0 + wr * 64;
  bool isq = nb < 4096;
  bool isk = (nb >= 4096) && (nb < 4608);
  bool isv = (nb >= 4608) && (nb < 5120);
  // ln(10000)/32
  float invf0 = expf((float)li * -0.2878231366242601f);
  float invf1 = expf((float)(16 + li) * -0.2878231366242601f);

#pragma unroll
  for (int mf = 0; mf < 4; ++mf) {
#pragma unroll
    for (int r = 0; r < 4; ++r) {
      int m = mb + mf * 16 + lg * 4 + r;
      int bb = m >> 11, s = m & 2047;
      if (isv) {
        // transposed V write: vt[(bb*HKV+hk)*DD + d][s]
        int hk = (nb - 4608) >> 8, hdb = (nb - 4608) & 255;
        unsigned short* dst = vo + ((size_t)(bb * HKV_ + hk) * DD + hdb) * SS + s;
#pragma unroll
        for (int nf = 0; nf < 4; ++nf)
          dst[(size_t)(nf * 16 + li) * SS] = f2bf(acc[mf][nf][r]);
      } else if (!isq && !isk) {  // gate: sigmoid
        int h = (nb - 5120) >> 8, hdb = (nb - 5120) & 255;
        unsigned short* dst = go + ((size_t)(bb * H_ + h) * SS + s) * DD + hdb;
#pragma unroll
        for (int nf = 0; nf < 4; ++nf) {
          float x = acc[mf][nf][r];
          dst[nf * 16 + li] = f2bf(1.f / (1.f + __expf(-x)));
        }
      } else {
        int hdb; unsigned short* dst;
        if (isq) { int h = nb >> 8; hdb = nb & 255;
                   dst = qo + ((size_t)(bb * H_ + h) * SS + s) * DD; }
        else     { int hk = (nb - 4096) >> 8; hdb = (nb - 4096) & 255;
                   dst = ko + ((size_t)(bb * HKV_ + hk) * SS + s) * DD; }
        if (hdb == 0) {
          // RoPE: hd = nf*16+li in [0,64); partner hd^32 is acc[mf][nf^2]
#pragma unroll
          for (int nf = 0; nf < 2; ++nf) {
            int fi = nf * 16 + li;
            float ang = (float)s * (nf ? invf1 : invf0);
            float sn, cs;
            sincosf(ang, &sn, &cs);
            float x1 = acc[mf][nf][r], x2 = acc[mf][nf + 2][r];
            dst[fi]      = f2bf(x1 * cs - x2 * sn);
            dst[fi + 32] = f2bf(x2 * cs + x1 * sn);
          }
        } else {
#pragma unroll
          for (int nf = 0; nf < 4; ++nf) dst[hdb + nf * 16 + li] = f2bf(acc[mf][nf][r]);
        }
      }
    }
  }
}

// -------- GEMM2: attn @ Wo^T -> fp32 out --------
__global__ __launch_bounds__(256) void ga_gemm_out(const unsigned short* __restrict__ A,
                                                   const unsigned short* __restrict__ Bt,
                                                   float* __restrict__ C) {
  __shared__ unsigned short As[128 * 32];
  __shared__ unsigned short Bs[128 * 32];
  int tid = threadIdx.x, lane = tid & 63, wid = tid >> 6;
  int wr = wid >> 1, wc = wid & 1;
  int n0, m0;
  xcd_swizzle_128(n0, m0);
  f32x4 acc[4][4];
  f32x4 z = {0.f, 0.f, 0.f, 0.f};
#pragma unroll
  for (int i = 0; i < 4; ++i)
#pragma unroll
    for (int j = 0; j < 4; ++j) acc[i][j] = z;

  gemm_loop<HD>(A, Bt, As, Bs, m0, n0, acc);

  int li = lane & 15, lg = lane >> 4;
#pragma unroll
  for (int mf = 0; mf < 4; ++mf)
#pragma unroll
    for (int r = 0; r < 4; ++r) {
      int m = m0 + wr * 64 + mf * 16 + lg * 4 + r;
#pragma unroll
      for (int nf = 0; nf < 4; ++nf) {
        int n = n0 + wc * 64 + nf * 16 + li;
        C[(size_t)m * EE + n] = acc[mf][nf][r];
      }
    }
}

// -------- flash attention: 4 waves, 64 q-rows/block, KV tiles of 32 --------
// T14 register staging: global->reg loads issued at loop top (no LDS alias,
// latency hides under compute), ds_write into the other buffer after compute,
// ONE __syncthreads per tile. Swizzled ds_write addresses, linear global reads.
__global__ __launch_bounds__(256, 2) void ga_attn(const unsigned short* __restrict__ qb,
                                                  const unsigned short* __restrict__ kb,
                                                  const unsigned short* __restrict__ vt,
                                                  const unsigned short* __restrict__ gb,
                                                  unsigned short* __restrict__ ob) {
  __shared__ unsigned short Ks[2][8192];   // [buf][32 kv x 256 d] swizzled chunks
  __shared__ unsigned short Vs[2][8192];   // [buf][256 d x 32 kv] swizzled chunks
  __shared__ unsigned short Pl[64][40];
  int tid = threadIdx.x, lane = tid & 63, wid = tid >> 6;
  int li = lane & 15, lg = lane >> 4;
  int q0 = ((int)gridDim.x - 1 - (int)blockIdx.x) * 64;   // heavy blocks dispatch first
  int bh = blockIdx.y;
  int b = bh >> 4, h = bh & 15, hk = h >> 3;
  const unsigned short* qp  = qb + ((size_t)(b * H_ + h) * SS) * DD;
  const unsigned short* kp  = kb + ((size_t)(b * HKV_ + hk) * SS) * DD;
  const unsigned short* vtp = vt + ((size_t)(b * HKV_ + hk) * DD) * SS;
  const unsigned short* gp  = gb + ((size_t)(b * H_ + h) * SS) * DD;

  // per-thread staging decode: 4 K-chunks + 4 V-chunks of 16B, linear global,
  // swizzled LDS destination (XOR within K row / V row)
  int kgo[4], klo[4], vgo[4], vlo[4];
#pragma unroll
  for (int it = 0; it < 4; ++it) {
    int c = (it * 4 + wid) * 64 + lane;          // 16B-chunk index 0..1023
    int kr = c >> 5, c16 = c & 31;               // K: 32 rows x 32 chunks
    kgo[it] = kr * DD + c16 * 8;                 // linear global (elems)
    klo[it] = kr * 256 + ((c16 ^ (kr & 7)) << 3);        // swizzled LDS (elems)
    int vd = c >> 2, vp4 = c & 3;                // V: 256 d-rows x 4 chunks
    vgo[it] = vd * SS + vp4 * 8;                 // linear global (elems, + kv0)
    vlo[it] = vd * 32 + ((vp4 ^ ((vd >> 1) & 3)) << 3);  // swizzled LDS (elems)
  }

  // Q fragments in registers: wave owns rows q0+wid*16..+16
  bf16x8 qf[8];
  {
    int qrow = q0 + wid * 16 + li;
#pragma unroll
    for (int ks = 0; ks < 8; ++ks)
      qf[ks] = *(const bf16x8*)(qp + (size_t)qrow * DD + ks * 32 + lg * 8);
  }

  f32x4 acc[16];
  f32x4 z = {0.f, 0.f, 0.f, 0.f};
#pragma unroll
  for (int f = 0; f < 16; ++f) acc[f] = z;
  float mrow[4] = {-1e30f, -1e30f, -1e30f, -1e30f};
  float lrow[4] = {0.f, 0.f, 0.f, 0.f};

  int nt = q0 / 32 + 2;
  int qwave = q0 + wid * 16;                      // wave's min q-row
  int vsw = (li >> 1) & 3;

  // prologue: stage tile 0 into buffer 0 (reg -> LDS)
  {
    uint4 kr4[4], vr4[4];
#pragma unroll
    for (int it = 0; it < 4; ++it) {
      kr4[it] = *(const uint4*)(kp + kgo[it]);
      vr4[it] = *(const uint4*)(vtp + vgo[it]);
    }
#pragma unroll
    for (int it = 0; it < 4; ++it) {
      *(uint4*)&Ks[0][klo[it]] = kr4[it];
      *(uint4*)&Vs[0][vlo[it]] = vr4[it];
    }
  }
  __syncthreads();

  for (int t = 0; t < nt; ++t) {
    int kv0 = t * 32;
    int cur = t & 1;
    uint4 kr4[4], vr4[4];
    bool pre = (t + 1 < nt);
    if (pre) {
      int kvn = kv0 + 32;
#pragma unroll
      for (int it = 0; it < 4; ++it) {
        kr4[it] = *(const uint4*)(kp + (size_t)kvn * DD + kgo[it]);
        vr4[it] = *(const uint4*)(vtp + kvn + vgo[it]);
      }
    }
    if (kv0 <= qwave + 15) {                      // wave-uniform causal activity
      // ---- QK^T ----
      f32x4 sc[2];
      sc[0] = z; sc[1] = z;
      __builtin_amdgcn_s_setprio(1);
#pragma unroll
      for (int ks = 0; ks < 8; ++ks)
#pragma unroll
        for (int nf = 0; nf < 2; ++nf) {
          int row = nf * 16 + li;
          bf16x8 kfr = *(const bf16x8*)&Ks[cur][row * 256 + (((ks * 4 + lg) ^ (li & 7)) << 3)];
          sc[nf] = __builtin_amdgcn_mfma_f32_16x16x32_bf16(qf[ks], kfr, sc[nf], 0, 0, 0);
        }
      __builtin_amdgcn_s_setprio(0);
      // ---- scale + causal mask (only diagonal tiles) ----
      int qbase = qwave + lg * 4;
      float sv[2][4];
      bool needmask = (kv0 + 31 > qwave);         // wave-uniform
#pragma unroll
      for (int nf = 0; nf < 2; ++nf) {
        int kvc = kv0 + nf * 16 + li;
#pragma unroll
        for (int r = 0; r < 4; ++r) {
          float v = sc[nf][r] * 0.0625f;
          if (needmask && kvc > qbase + r) v = -1e30f;
          sv[nf][r] = v;
        }
      }
      // ---- online softmax (defer-max, THR=8) ----
      float pm[4];
#pragma unroll
      for (int r = 0; r < 4; ++r) pm[r] = fmaxf(sv[0][r], sv[1][r]);
#pragma unroll
      for (int off = 1; off < 16; off <<= 1)
#pragma unroll
        for (int r = 0; r < 4; ++r) pm[r] = fmaxf(pm[r], __shfl_xor(pm[r], off));
      bool ok = true;
#pragma unroll
      for (int r = 0; r < 4; ++r) ok = ok && (pm[r] - mrow[r] <= 8.f);
      if (!__all(ok)) {
#pragma unroll
        for (int r = 0; r < 4; ++r) {
          float nm = fmaxf(mrow[r], pm[r]);
          float scl = __expf(mrow[r] - nm);
          mrow[r] = nm;
          lrow[r] *= scl;
#pragma unroll
          for (int f = 0; f < 16; ++f) acc[f][r] *= scl;
        }
      }
      float rs[4] = {0.f, 0.f, 0.f, 0.f};
#pragma unroll
      for (int nf = 0; nf < 2; ++nf)
#pragma unroll
        for (int r = 0; r < 4; ++r) {
          float p = __expf(sv[nf][r] - mrow[r]);
          rs[r] += p;
          Pl[wid * 16 + lg * 4 + r][nf * 16 + li] = f2bf(p);
        }
#pragma unroll
      for (int off = 1; off < 16; off <<= 1)
#pragma unroll
        for (int r = 0; r < 4; ++r) rs[r] += __shfl_xor(rs[r], off);
#pragma unroll
      for (int r = 0; r < 4; ++r) lrow[r] += rs[r];
      // ---- PV: attn += P @ V (plain b128 reads of swizzled V^T tile) ----
      // P is wave-private; compiler orders the Pl writes->read via lgkmcnt.
      bf16x8 pa = *(const bf16x8*)&Pl[wid * 16 + li][lg * 8];
      __builtin_amdgcn_s_setprio(1);
#pragma unroll
      for (int f = 0; f < 16; ++f) {
        bf16x8 bv = *(const bf16x8*)&Vs[cur][(f * 16 + li) * 32 + ((lg ^ vsw) << 3)];
        acc[f] = __builtin_amdgcn_mfma_f32_16x16x32_bf16(pa, bv, acc[f], 0, 0, 0);
      }
      __builtin_amdgcn_s_setprio(0);
    }
    if (pre) {
      // write next tile into the other buffer (its readers finished last iter;
      // compiler inserts the vmcnt wait here, after the compute phase)
#pragma unroll
      for (int it = 0; it < 4; ++it) {
        *(uint4*)&Ks[cur ^ 1][klo[it]] = kr4[it];
        *(uint4*)&Vs[cur ^ 1][vlo[it]] = vr4[it];
      }
    }
    __syncthreads();                              // writes visible; reads done
  }
  // ---- epilogue: normalize, gate, store ----
  float inv[4];
#pragma unroll
  for (int r = 0; r < 4; ++r) inv[r] = 1.f / lrow[r];
  int qgl_base = q0 + wid * 16 + lg * 4;
#pragma unroll
  for (int f = 0; f < 16; ++f) {
    int d = f * 16 + li;
#pragma unroll
    for (int r = 0; r < 4; ++r) {
      int qgl = qgl_base + r;
      float g = bf2f(gp[(size_t)qgl * DD + d]);
      float v = acc[f][r] * inv[r] * g;
      ob[((size_t)(b * SS + qgl)) * HD + h * DD + d] = f2bf(v);
    }
  }
}

extern "C" void kernel_launch(void* const* d_in, const int* in_sizes, int n_in,
                              void* d_out, int out_size, void* d_ws, size_t ws_size,
                              hipStream_t stream) {
  (void)in_sizes; (void)n_in; (void)out_size;
  const float* hs = (const float*)d_in[0];
  const float* Wq = (const float*)d_in[1];
  const float* Wk = (const float*)d_in[2];
  const float* Wv = (const float*)d_in[3];
  const float* Wg = (const float*)d_in[4];
  const float* Wo = (const float*)d_in[5];
  float* out = (float*)d_out;

  // workspace layout (bytes)
  const size_t off_X    = 0;                       // 4096x2048 bf16
  const size_t off_Wcat = off_X    + 16777216;     // 9216x2048 bf16 (transposed)
  const size_t off_Wot  = off_Wcat + 37748736;     // 2048x4096 bf16 (transposed)
  const size_t off_q    = off_Wot  + 16777216;     // B,H,S,D bf16
  const size_t off_k    = off_q    + 33554432;     // B,HKV,S,D
  const size_t off_v    = off_k    + 4194304;      // B,HKV,D,S (TRANSPOSED)
  const size_t off_g    = off_v    + 4194304;      // B,H,S,D
  const size_t off_attn = off_g    + 33554432;     // 4096x4096 bf16
  const size_t need     = off_attn + 33554432;     // ~172 MB
  if (ws_size < need) return;  // insufficient scratch: leave output poisoned

  char* ws = (char*)d_ws;
  unsigned short* Xbf   = (unsigned short*)(ws + off_X);
  unsigned short* Wcat  = (unsigned short*)(ws + off_Wcat);
  unsigned short* Wot   = (unsigned short*)(ws + off_Wot);
  unsigned short* qbf   = (unsigned short*)(ws + off_q);
  unsigned short* kbf   = (unsigned short*)(ws + off_k);
  unsigned short* vbf   = (unsigned short*)(ws + off_v);
  unsigned short* gbf   = (unsigned short*)(ws + off_g);
  unsigned short* attnb = (unsigned short*)(ws + off_attn);

  // 1) convert hidden_states to bf16
  ga_cvt<<<8192, 256, 0, stream>>>(hs, Xbf, MTOK * EE);
  // 2) pack weights (transposed, bf16)
  ga_pack_qkvg<<<dim3(144, 32), 256, 0, stream>>>(Wq, Wk, Wv, Wg, Wcat);
  ga_transpose_wo<<<dim3(32, 64), 256, 0, stream>>>(Wo, Wot, HD, EE);
  // 3) fused QKVG projection + RoPE + sigmoid (V written transposed)
  ga_gemm_qkvg<<<dim3(72, 32), 256, 0, stream>>>(Xbf, Wcat, qbf, kbf, vbf, gbf);
  // 4) causal GQA flash attention + gating
  ga_attn<<<dim3(32, 32), 256, 0, stream>>>(qbf, kbf, vbf, gbf, attnb);
  // 5) output projection (fp32 out)
  ga_gemm_out<<<dim3(16, 32), 256, 0, stream>>>(attnb, Wot, out);
}

// Round 6
// 683.347 us; speedup vs baseline: 1.4114x; 1.4114x over previous
//
#include <hip/hip_runtime.h>
#include <hip/hip_bf16.h>
#include <cstdint>

typedef __attribute__((ext_vector_type(8))) short bf16x8;
typedef __attribute__((ext_vector_type(4))) float f32x4;

#define H_   16
#define HKV_ 2
#define DD   256
#define BB   2
#define SS   2048
#define EE   2048
#define MTOK (BB*SS)     // 4096
#define HD   (H_*DD)     // 4096

static __device__ __forceinline__ unsigned short f2bf(float f) {
  union { float f; unsigned u; } v; v.f = f;
  unsigned r = v.u + 0x7fffu + ((v.u >> 16) & 1u);
  return (unsigned short)(r >> 16);
}
static __device__ __forceinline__ float bf2f(unsigned short h) {
  union { unsigned u; float f; } v; v.u = ((unsigned)h) << 16;
  return v.f;
}

static __device__ __forceinline__ void gll16(const unsigned short* g, unsigned short* l) {
  __builtin_amdgcn_global_load_lds(
      (const __attribute__((address_space(1))) unsigned int*)g,
      (__attribute__((address_space(3))) unsigned int*)l, 16, 0, 0);
}

// ---------------- fp32 -> bf16 convert (vectorized) ----------------
__global__ __launch_bounds__(256) void ga_cvt(const float* __restrict__ in,
                                              unsigned short* __restrict__ out, int n) {
  int i = (blockIdx.x * 256 + threadIdx.x) * 4;
  if (i >= n) return;
  float4 v = *(const float4*)(in + i);
  ushort4 o;
  o.x = f2bf(v.x); o.y = f2bf(v.y); o.z = f2bf(v.z); o.w = f2bf(v.w);
  *(ushort4*)(out + i) = o;
}

// -------- transpose+convert: out[c][r] = bf16(in[r][c]), in is R x C --------
__global__ __launch_bounds__(256) void ga_transpose_wo(const float* __restrict__ in,
                                                       unsigned short* __restrict__ out,
                                                       int R, int C) {
  __shared__ float tile[64][65];
  int c0 = blockIdx.x * 64, r0 = blockIdx.y * 64;
  int tid = threadIdx.x;
#pragma unroll
  for (int it = 0; it < 16; ++it) {
    int idx = it * 256 + tid; int rr = idx >> 6, cc = idx & 63;
    tile[rr][cc] = in[(size_t)(r0 + rr) * C + c0 + cc];
  }
  __syncthreads();
#pragma unroll
  for (int it = 0; it < 16; ++it) {
    int idx = it * 256 + tid; int rr = idx >> 6, cc = idx & 63;
    out[(size_t)(c0 + rr) * R + r0 + cc] = f2bf(tile[cc][rr]);
  }
}

// -------- pack [Wq|Wk|Wv|Wg] transposed: out[n][k], n in [0,9216) --------
__global__ __launch_bounds__(256) void ga_pack_qkvg(const float* __restrict__ Wq,
                                                    const float* __restrict__ Wk,
                                                    const float* __restrict__ Wv,
                                                    const float* __restrict__ Wg,
                                                    unsigned short* __restrict__ out) {
  __shared__ float tile[64][65];
  int n0 = blockIdx.x * 64, k0 = blockIdx.y * 64;
  const float* src; int C, cbase;
  if (n0 < 4096)      { src = Wq; C = 4096; cbase = n0; }
  else if (n0 < 4608) { src = Wk; C = 512;  cbase = n0 - 4096; }
  else if (n0 < 5120) { src = Wv; C = 512;  cbase = n0 - 4608; }
  else                { src = Wg; C = 4096; cbase = n0 - 5120; }
  int tid = threadIdx.x;
#pragma unroll
  for (int it = 0; it < 16; ++it) {
    int idx = it * 256 + tid; int rr = idx >> 6, cc = idx & 63;
    tile[rr][cc] = src[(size_t)(k0 + rr) * C + cbase + cc];
  }
  __syncthreads();
#pragma unroll
  for (int it = 0; it < 16; ++it) {
    int idx = it * 256 + tid; int rr = idx >> 6, cc = idx & 63;
    out[(size_t)(n0 + rr) * EE + k0 + cc] = f2bf(tile[cc][rr]);
  }
}

// -------- shared 128x128 GEMM main loop (A[M][K] @ Bt[N][K]^T) --------
template<int KDIM>
static __device__ __forceinline__ void gemm_loop(const unsigned short* __restrict__ A,
                                                 const unsigned short* __restrict__ Bt,
                                                 unsigned short* As, unsigned short* Bs,
                                                 int m0, int n0, f32x4 acc[4][4]) {
  int tid = threadIdx.x, lane = tid & 63, wid = tid >> 6;
  int wr = wid >> 1, wc = wid & 1;
  for (int k0 = 0; k0 < KDIM; k0 += 32) {
    __syncthreads();
#pragma unroll
    for (int r2 = 0; r2 < 2; ++r2) {
      int c = r2 * 256 + wid * 64 + lane;
      int row = c >> 2, cb = c & 3;
      gll16(A  + (size_t)(m0 + row) * KDIM + k0 + cb * 8, As + (r2 * 256 + wid * 64) * 8);
      gll16(Bt + (size_t)(n0 + row) * KDIM + k0 + cb * 8, Bs + (r2 * 256 + wid * 64) * 8);
    }
    __syncthreads();
    bf16x8 af[4], bfv[4];
#pragma unroll
    for (int mf = 0; mf < 4; ++mf)
      af[mf] = *(const bf16x8*)&As[(wr * 64 + mf * 16 + (lane & 15)) * 32 + (lane >> 4) * 8];
#pragma unroll
    for (int nf = 0; nf < 4; ++nf)
      bfv[nf] = *(const bf16x8*)&Bs[(wc * 64 + nf * 16 + (lane & 15)) * 32 + (lane >> 4) * 8];
#pragma unroll
    for (int mf = 0; mf < 4; ++mf)
#pragma unroll
      for (int nf = 0; nf < 4; ++nf)
        acc[mf][nf] = __builtin_amdgcn_mfma_f32_16x16x32_bf16(af[mf], bfv[nf], acc[mf][nf], 0, 0, 0);
  }
}

// bijective XCD swizzle over the linear grid (nwg divisible by 8)
static __device__ __forceinline__ void xcd_swizzle_128(int& n0, int& m0) {
  int gx = gridDim.x;
  int nwg = gx * gridDim.y;
  int lin = blockIdx.y * gx + blockIdx.x;
  int cpx = nwg >> 3;
  int swz = (lin & 7) * cpx + (lin >> 3);
  n0 = (swz % gx) * 128;
  m0 = (swz / gx) * 128;
}

// -------- GEMM1: X @ Wcat^T with fused RoPE/sigmoid scatter epilogue --------
// V is written TRANSPOSED to global: vt[b][hk][d][s]  (enables plain-load PV)
__global__ __launch_bounds__(256) void ga_gemm_qkvg(const unsigned short* __restrict__ A,
                                                    const unsigned short* __restrict__ Bt,
                                                    unsigned short* __restrict__ qo,
                                                    unsigned short* __restrict__ ko,
                                                    unsigned short* __restrict__ vo,
                                                    unsigned short* __restrict__ go) {
  __shared__ unsigned short As[128 * 32];
  __shared__ unsigned short Bs[128 * 32];
  int tid = threadIdx.x, lane = tid & 63, wid = tid >> 6;
  int wr = wid >> 1, wc = wid & 1;
  int n0, m0;
  xcd_swizzle_128(n0, m0);
  f32x4 acc[4][4];
  f32x4 z = {0.f, 0.f, 0.f, 0.f};
#pragma unroll
  for (int i = 0; i < 4; ++i)
#pragma unroll
    for (int j = 0; j < 4; ++j) acc[i][j] = z;

  gemm_loop<EE>(A, Bt, As, Bs, m0, n0, acc);

  int li = lane & 15, lg = lane >> 4;
  int nb = n0 + wc * 64;      // 64-aligned col block (single region, single head)
  int mb = m0 + wr * 64;
  bool isq = nb < 4096;
  bool isk = (nb >= 4096) && (nb < 4608);
  bool isv = (nb >= 4608) && (nb < 5120);
  // ln(10000)/32
  float invf0 = expf((float)li * -0.2878231366242601f);
  float invf1 = expf((float)(16 + li) * -0.2878231366242601f);

#pragma unroll
  for (int mf = 0; mf < 4; ++mf) {
#pragma unroll
    for (int r = 0; r < 4; ++r) {
      int m = mb + mf * 16 + lg * 4 + r;
      int bb = m >> 11, s = m & 2047;
      if (isv) {
        // transposed V write: vt[(bb*HKV+hk)*DD + d][s]
        int hk = (nb - 4608) >> 8, hdb = (nb - 4608) & 255;
        unsigned short* dst = vo + ((size_t)(bb * HKV_ + hk) * DD + hdb) * SS + s;
#pragma unroll
        for (int nf = 0; nf < 4; ++nf)
          dst[(size_t)(nf * 16 + li) * SS] = f2bf(acc[mf][nf][r]);
      } else if (!isq && !isk) {  // gate: sigmoid
        int h = (nb - 5120) >> 8, hdb = (nb - 5120) & 255;
        unsigned short* dst = go + ((size_t)(bb * H_ + h) * SS + s) * DD + hdb;
#pragma unroll
        for (int nf = 0; nf < 4; ++nf) {
          float x = acc[mf][nf][r];
          dst[nf * 16 + li] = f2bf(1.f / (1.f + __expf(-x)));
        }
      } else {
        int hdb; unsigned short* dst;
        if (isq) { int h = nb >> 8; hdb = nb & 255;
                   dst = qo + ((size_t)(bb * H_ + h) * SS + s) * DD; }
        else     { int hk = (nb - 4096) >> 8; hdb = (nb - 4096) & 255;
                   dst = ko + ((size_t)(bb * HKV_ + hk) * SS + s) * DD; }
        if (hdb == 0) {
          // RoPE: hd = nf*16+li in [0,64); partner hd^32 is acc[mf][nf^2]
#pragma unroll
          for (int nf = 0; nf < 2; ++nf) {
            int fi = nf * 16 + li;
            float ang = (float)s * (nf ? invf1 : invf0);
            float sn, cs;
            sincosf(ang, &sn, &cs);
            float x1 = acc[mf][nf][r], x2 = acc[mf][nf + 2][r];
            dst[fi]      = f2bf(x1 * cs - x2 * sn);
            dst[fi + 32] = f2bf(x2 * cs + x1 * sn);
          }
        } else {
#pragma unroll
          for (int nf = 0; nf < 4; ++nf) dst[hdb + nf * 16 + li] = f2bf(acc[mf][nf][r]);
        }
      }
    }
  }
}

// -------- GEMM2: attn @ Wo^T -> fp32 out --------
__global__ __launch_bounds__(256) void ga_gemm_out(const unsigned short* __restrict__ A,
                                                   const unsigned short* __restrict__ Bt,
                                                   float* __restrict__ C) {
  __shared__ unsigned short As[128 * 32];
  __shared__ unsigned short Bs[128 * 32];
  int tid = threadIdx.x, lane = tid & 63, wid = tid >> 6;
  int wr = wid >> 1, wc = wid & 1;
  int n0, m0;
  xcd_swizzle_128(n0, m0);
  f32x4 acc[4][4];
  f32x4 z = {0.f, 0.f, 0.f, 0.f};
#pragma unroll
  for (int i = 0; i < 4; ++i)
#pragma unroll
    for (int j = 0; j < 4; ++j) acc[i][j] = z;

  gemm_loop<HD>(A, Bt, As, Bs, m0, n0, acc);

  int li = lane & 15, lg = lane >> 4;
#pragma unroll
  for (int mf = 0; mf < 4; ++mf)
#pragma unroll
    for (int r = 0; r < 4; ++r) {
      int m = m0 + wr * 64 + mf * 16 + lg * 4 + r;
#pragma unroll
      for (int nf = 0; nf < 4; ++nf) {
        int n = n0 + wc * 64 + nf * 16 + li;
        C[(size_t)m * EE + n] = acc[mf][nf][r];
      }
    }
}

// -------- flash attention: 8 waves, 128 q-rows/block, KV tiles of 32 --------
// Double-buffered K/V via global_load_lds (pre-swizzled global source, linear
// LDS dest), counted vmcnt(4) so next tile's loads stay in flight across the
// barrier. 8 waves => 2-4 waves/SIMD for latency hiding (R4 had 1/SIMD).
__global__ __launch_bounds__(512, 4) void ga_attn(const unsigned short* __restrict__ qb,
                                                  const unsigned short* __restrict__ kb,
                                                  const unsigned short* __restrict__ vt,
                                                  const unsigned short* __restrict__ gb,
                                                  unsigned short* __restrict__ ob) {
  __shared__ unsigned short Ks[2][8192];   // [buf][32 kv x 256 d] chunk-swizzled
  __shared__ unsigned short Vs[2][8192];   // [buf][256 d x 32 kv] chunk-swizzled
  __shared__ unsigned short Pl[128][40];
  int tid = threadIdx.x, lane = tid & 63, wid = tid >> 6;   // wid 0..7
  int li = lane & 15, lg = lane >> 4;
  int q0 = ((int)gridDim.x - 1 - (int)blockIdx.x) * 128;    // heavy blocks first
  int bh = blockIdx.y;
  int b = bh >> 4, h = bh & 15, hk = h >> 3;
  const unsigned short* qp  = qb + ((size_t)(b * H_ + h) * SS) * DD;
  const unsigned short* kp  = kb + ((size_t)(b * HKV_ + hk) * SS) * DD;
  const unsigned short* vtp = vt + ((size_t)(b * HKV_ + hk) * DD) * SS;
  const unsigned short* gp  = gb + ((size_t)(b * H_ + h) * SS) * DD;

  // per-thread staging decode: 2 K-chunks + 2 V-chunks of 16B each per tile.
  // global source pre-swizzled, LDS dest linear (both-sides rule).
  int kgo[2], vgo[2], lo[2];
#pragma unroll
  for (int it = 0; it < 2; ++it) {
    int c = it * 512 + tid;                      // 16B-chunk index 0..1023
    int kr = c >> 5, c16 = c & 31;               // K: 32 rows x 32 chunks
    kgo[it] = kr * DD + ((c16 ^ (kr & 7)) << 3); // swizzled global (elems)
    int vd = c >> 2, vp4 = c & 3;                // V: 256 d-rows x 4 chunks
    vgo[it] = vd * SS + ((vp4 ^ ((vd >> 1) & 3)) << 3);  // elems, + kv0
    lo[it] = (it * 8 + wid) * 512;               // wave-uniform LDS base (elems)
  }

  // Q fragments in registers: wave owns rows q0+wid*16..+16
  bf16x8 qf[8];
  {
    int qrow = q0 + wid * 16 + li;
#pragma unroll
    for (int ks = 0; ks < 8; ++ks)
      qf[ks] = *(const bf16x8*)(qp + (size_t)qrow * DD + ks * 32 + lg * 8);
  }

  f32x4 acc[16];
  f32x4 z = {0.f, 0.f, 0.f, 0.f};
#pragma unroll
  for (int f = 0; f < 16; ++f) acc[f] = z;
  float mrow[4] = {-1e30f, -1e30f, -1e30f, -1e30f};
  float lrow[4] = {0.f, 0.f, 0.f, 0.f};

  int nt = q0 / 32 + 4;
  int qwave = q0 + wid * 16;                      // wave's min q-row
  int vsw = (li >> 1) & 3;

  // prologue: stage tile 0 into buffer 0
#pragma unroll
  for (int it = 0; it < 2; ++it) {
    gll16(kp + kgo[it], &Ks[0][lo[it]]);
    gll16(vtp + vgo[it], &Vs[0][lo[it]]);
  }

  for (int t = 0; t < nt; ++t) {
    int kv0 = t * 32;
    int cur = t & 1;
    if (t + 1 < nt) {
      int kvn = kv0 + 32;
#pragma unroll
      for (int it = 0; it < 2; ++it) {
        gll16(kp + (size_t)kvn * DD + kgo[it], &Ks[cur ^ 1][lo[it]]);
        gll16(vtp + kvn + vgo[it],             &Vs[cur ^ 1][lo[it]]);
      }
      asm volatile("s_waitcnt vmcnt(4)" ::: "memory");   // current buf landed
    } else {
      asm volatile("s_waitcnt vmcnt(0)" ::: "memory");
    }
    __builtin_amdgcn_s_barrier();                        // all waves' loads in
    __builtin_amdgcn_sched_barrier(0);
    if (kv0 <= qwave + 15) {                      // wave-uniform causal activity
      // ---- QK^T ----
      f32x4 sc[2];
      sc[0] = z; sc[1] = z;
      __builtin_amdgcn_s_setprio(1);
#pragma unroll
      for (int ks = 0; ks < 8; ++ks)
#pragma unroll
        for (int nf = 0; nf < 2; ++nf) {
          int row = nf * 16 + li;
          bf16x8 kfr = *(const bf16x8*)&Ks[cur][row * 256 + (((ks * 4 + lg) ^ (li & 7)) << 3)];
          sc[nf] = __builtin_amdgcn_mfma_f32_16x16x32_bf16(qf[ks], kfr, sc[nf], 0, 0, 0);
        }
      __builtin_amdgcn_s_setprio(0);
      // ---- scale + causal mask (only diagonal tiles) ----
      int qbase = qwave + lg * 4;
      float sv[2][4];
      bool needmask = (kv0 + 31 > qwave);         // wave-uniform
#pragma unroll
      for (int nf = 0; nf < 2; ++nf) {
        int kvc = kv0 + nf * 16 + li;
#pragma unroll
        for (int r = 0; r < 4; ++r) {
          float v = sc[nf][r] * 0.0625f;
          if (needmask && kvc > qbase + r) v = -1e30f;
          sv[nf][r] = v;
        }
      }
      // ---- online softmax (defer-max, THR=8) ----
      float pm[4];
#pragma unroll
      for (int r = 0; r < 4; ++r) pm[r] = fmaxf(sv[0][r], sv[1][r]);
#pragma unroll
      for (int off = 1; off < 16; off <<= 1)
#pragma unroll
        for (int r = 0; r < 4; ++r) pm[r] = fmaxf(pm[r], __shfl_xor(pm[r], off));
      bool ok = true;
#pragma unroll
      for (int r = 0; r < 4; ++r) ok = ok && (pm[r] - mrow[r] <= 8.f);
      if (!__all(ok)) {
#pragma unroll
        for (int r = 0; r < 4; ++r) {
          float nm = fmaxf(mrow[r], pm[r]);
          float scl = __expf(mrow[r] - nm);
          mrow[r] = nm;
          lrow[r] *= scl;
#pragma unroll
          for (int f = 0; f < 16; ++f) acc[f][r] *= scl;
        }
      }
      float rs[4] = {0.f, 0.f, 0.f, 0.f};
#pragma unroll
      for (int nf = 0; nf < 2; ++nf)
#pragma unroll
        for (int r = 0; r < 4; ++r) {
          float p = __expf(sv[nf][r] - mrow[r]);
          rs[r] += p;
          Pl[wid * 16 + lg * 4 + r][nf * 16 + li] = f2bf(p);
        }
#pragma unroll
      for (int off = 1; off < 16; off <<= 1)
#pragma unroll
        for (int r = 0; r < 4; ++r) rs[r] += __shfl_xor(rs[r], off);
#pragma unroll
      for (int r = 0; r < 4; ++r) lrow[r] += rs[r];
      // ---- PV: attn += P @ V (plain b128 reads of swizzled V^T tile) ----
      // P is wave-private; compiler orders the Pl writes->read via lgkmcnt.
      bf16x8 pa = *(const bf16x8*)&Pl[wid * 16 + li][lg * 8];
      __builtin_amdgcn_s_setprio(1);
#pragma unroll
      for (int f = 0; f < 16; ++f) {
        bf16x8 bv = *(const bf16x8*)&Vs[cur][(f * 16 + li) * 32 + ((lg ^ vsw) << 3)];
        acc[f] = __builtin_amdgcn_mfma_f32_16x16x32_bf16(pa, bv, acc[f], 0, 0, 0);
      }
      __builtin_amdgcn_s_setprio(0);
    }
    __builtin_amdgcn_sched_barrier(0);
    __builtin_amdgcn_s_barrier();                 // all waves done reading buf[cur]
  }
  // ---- epilogue: normalize, gate, store ----
  float inv[4];
#pragma unroll
  for (int r = 0; r < 4; ++r) inv[r] = 1.f / lrow[r];
  int qgl_base = q0 + wid * 16 + lg * 4;
#pragma unroll
  for (int f = 0; f < 16; ++f) {
    int d = f * 16 + li;
#pragma unroll
    for (int r = 0; r < 4; ++r) {
      int qgl = qgl_base + r;
      float g = bf2f(gp[(size_t)qgl * DD + d]);
      float v = acc[f][r] * inv[r] * g;
      ob[((size_t)(b * SS + qgl)) * HD + h * DD + d] = f2bf(v);
    }
  }
}

extern "C" void kernel_launch(void* const* d_in, const int* in_sizes, int n_in,
                              void* d_out, int out_size, void* d_ws, size_t ws_size,
                              hipStream_t stream) {
  (void)in_sizes; (void)n_in; (void)out_size;
  const float* hs = (const float*)d_in[0];
  const float* Wq = (const float*)d_in[1];
  const float* Wk = (const float*)d_in[2];
  const float* Wv = (const float*)d_in[3];
  const float* Wg = (const float*)d_in[4];
  const float* Wo = (const float*)d_in[5];
  float* out = (float*)d_out;

  // workspace layout (bytes)
  const size_t off_X    = 0;                       // 4096x2048 bf16
  const size_t off_Wcat = off_X    + 16777216;     // 9216x2048 bf16 (transposed)
  const size_t off_Wot  = off_Wcat + 37748736;     // 2048x4096 bf16 (transposed)
  const size_t off_q    = off_Wot  + 16777216;     // B,H,S,D bf16
  const size_t off_k    = off_q    + 33554432;     // B,HKV,S,D
  const size_t off_v    = off_k    + 4194304;      // B,HKV,D,S (TRANSPOSED)
  const size_t off_g    = off_v    + 4194304;      // B,H,S,D
  const size_t off_attn = off_g    + 33554432;     // 4096x4096 bf16
  const size_t need     = off_attn + 33554432;     // ~172 MB
  if (ws_size < need) return;  // insufficient scratch: leave output poisoned

  char* ws = (char*)d_ws;
  unsigned short* Xbf   = (unsigned short*)(ws + off_X);
  unsigned short* Wcat  = (unsigned short*)(ws + off_Wcat);
  unsigned short* Wot   = (unsigned short*)(ws + off_Wot);
  unsigned short* qbf   = (unsigned short*)(ws + off_q);
  unsigned short* kbf   = (unsigned short*)(ws + off_k);
  unsigned short* vbf   = (unsigned short*)(ws + off_v);
  unsigned short* gbf   = (unsigned short*)(ws + off_g);
  unsigned short* attnb = (unsigned short*)(ws + off_attn);

  // 1) convert hidden_states to bf16
  ga_cvt<<<8192, 256, 0, stream>>>(hs, Xbf, MTOK * EE);
  // 2) pack weights (transposed, bf16)
  ga_pack_qkvg<<<dim3(144, 32), 256, 0, stream>>>(Wq, Wk, Wv, Wg, Wcat);
  ga_transpose_wo<<<dim3(32, 64), 256, 0, stream>>>(Wo, Wot, HD, EE);
  // 3) fused QKVG projection + RoPE + sigmoid (V written transposed)
  ga_gemm_qkvg<<<dim3(72, 32), 256, 0, stream>>>(Xbf, Wcat, qbf, kbf, vbf, gbf);
  // 4) causal GQA flash attention + gating (8 waves, 128 q-rows/block)
  ga_attn<<<dim3(16, 32), 512, 0, stream>>>(qbf, kbf, vbf, gbf, attnb);
  // 5) output projection (fp32 out)
  ga_gemm_out<<<dim3(16, 32), 256, 0, stream>>>(attnb, Wot, out);
}